// Round 6
// baseline (27.290 us; speedup 1.0000x reference)
//
#include <hip/hip_runtime.h>
#include <math.h>

#define FFT_N   4096
#define THREADS 256
#define RH 0.70710678118654752f
#define C16 0.92387953251128676f     // cos(2*pi/16)
#define S16 0.38268343236508977f     // sin(2*pi/16)
#define NEG2PI_256  (-2.45436926061702597e-2f)   // -2*pi/256
#define NEG2PI_4096 (-1.53398078788564123e-3f)   // -2*pi/4096

// Output-position map of dft16: X[k] lives in v[POS(k)].
#define POS(k) ((((k) & 3) << 2) | ((k) >> 2))

__device__ __forceinline__ float2 cmul(float2 a, float2 b) {
    return make_float2(a.x * b.x - a.y * b.y, a.x * b.y + a.y * b.x);
}

// In-place DFT-4 (W4 = -i): natural in, natural out.
__device__ __forceinline__ void dft4(float2& a, float2& b, float2& c, float2& d) {
    float2 t0 = make_float2(a.x + c.x, a.y + c.y);
    float2 t1 = make_float2(a.x - c.x, a.y - c.y);
    float2 t2 = make_float2(b.x + d.x, b.y + d.y);
    float2 t3 = make_float2(b.y - d.y, d.x - b.x);   // -i * (b - d)
    a = make_float2(t0.x + t2.x, t0.y + t2.y);
    b = make_float2(t1.x + t3.x, t1.y + t3.y);
    c = make_float2(t0.x - t2.x, t0.y - t2.y);
    d = make_float2(t1.x - t3.x, t1.y - t3.y);
}

// Multiply by W16^E = exp(-2*pi*i*E/16); constant-folded forms.
template<int E>
__device__ __forceinline__ float2 mw16(float2 z) {
    if constexpr (E == 0) return z;
    else if constexpr (E == 4) return make_float2(z.y, -z.x);                    // -i
    else if constexpr (E == 2) return make_float2(RH * (z.x + z.y), RH * (z.y - z.x));
    else if constexpr (E == 6) return make_float2(RH * (z.y - z.x), -RH * (z.x + z.y));
    else if constexpr (E == 1) return cmul(z, make_float2(C16, -S16));
    else if constexpr (E == 3) return cmul(z, make_float2(S16, -C16));
    else /* E == 9 */          return cmul(z, make_float2(-C16, S16));
}

// 16-point DFT, natural input order; output X[k] at v[POS(k)].
__device__ __forceinline__ void dft16(float2 (&v)[16]) {
    dft4(v[0], v[4], v[8],  v[12]);
    dft4(v[1], v[5], v[9],  v[13]);
    dft4(v[2], v[6], v[10], v[14]);
    dft4(v[3], v[7], v[11], v[15]);
    v[5]  = mw16<1>(v[5]);   v[9]  = mw16<2>(v[9]);   v[13] = mw16<3>(v[13]);
    v[6]  = mw16<2>(v[6]);   v[10] = mw16<4>(v[10]);  v[14] = mw16<6>(v[14]);
    v[7]  = mw16<3>(v[7]);   v[11] = mw16<6>(v[11]);  v[15] = mw16<9>(v[15]);
    dft4(v[0],  v[1],  v[2],  v[3]);
    dft4(v[4],  v[5],  v[6],  v[7]);
    dft4(v[8],  v[9],  v[10], v[11]);
    dft4(v[12], v[13], v[14], v[15]);
}

// 4096 = 16*16*16 DIT: n = n1 + 16*n2 + 256*n3, k = k3 + 16*k2 + 256*k1.
__global__ __launch_bounds__(THREADS)
void fft4096_r16(const float* __restrict__ xre, const float* __restrict__ xim,
                 float* __restrict__ yre, float* __restrict__ yim)
{
    __shared__ float2 sd[FFT_N];   // 32 KB -> 5 blocks/CU

    const int t  = threadIdx.x;
    const int lo = t & 15;         // stage A: n1 ; stage B: n1 ; stage C: k3
    const int hi = t >> 4;         // stage A: n2 ; stage B: k3 ; stage C: k2
    const size_t off = (size_t)blockIdx.x * FFT_N;
    const float* xr = xre + off;
    const float* xi = xim + off;

    // ---- Stage A: coalesced stride-256 gather, DFT16 over n3 ----
    float2 v[16];
    #pragma unroll
    for (int n3 = 0; n3 < 16; ++n3) {
        v[n3].x = xr[t + (n3 << 8)];
        v[n3].y = xi[t + (n3 << 8)];
    }
    dft16(v);

    // Twiddle W256^{n2*k3}, depth-2 factorization: tw(k3) = b[k3&3]*c[k3>>2].
    // Write RT1: sd[t + 256*k3]  (uniform 4/pair-bank)
    {
        float sn, cs;
        __sincosf((float)hi * NEG2PI_256, &sn, &cs);
        float2 b[4], c[4];
        b[0] = make_float2(1.f, 0.f);
        b[1] = make_float2(cs, sn);
        b[2] = cmul(b[1], b[1]);
        b[3] = cmul(b[2], b[1]);
        c[0] = make_float2(1.f, 0.f);
        c[1] = cmul(b[2], b[2]);        // W256^{4*hi}
        c[2] = cmul(c[1], c[1]);
        c[3] = cmul(c[2], c[1]);
        #pragma unroll
        for (int k3 = 0; k3 < 16; ++k3) {
            float2 z = v[POS(k3)];
            if (k3 & 3)  z = cmul(z, b[k3 & 3]);
            if (k3 >> 2) z = cmul(z, c[k3 >> 2]);
            sd[t + (k3 << 8)] = z;
        }
    }
    __syncthreads();

    // RT1 read: u[n2] = sd[n1 + 16*n2 + 256*k3]  (uniform 4/pair-bank)
    #pragma unroll
    for (int n2 = 0; n2 < 16; ++n2)
        v[n2] = sd[lo + (n2 << 4) + (hi << 8)];
    __syncthreads();   // sd reused by RT2 writes

    // ---- Stage B: DFT16 over n2 ----
    dft16(v);

    // Twiddle W4096^{n1*(k3+16*k2)} = P * w[k2&3] * z[k2>>2], P = W4096^{n1*k3}.
    // Write RT2 XOR-swizzled: sd[(k3^n1) + 16*k2 + 256*n1]  (uniform 4/pair-bank)
    {
        float sn, cs;
        __sincosf((float)(lo * hi) * NEG2PI_4096, &sn, &cs);
        const float2 P = make_float2(cs, sn);
        __sincosf((float)lo * NEG2PI_256, &sn, &cs);
        float2 w1 = make_float2(cs, sn);          // W256^{n1} = W4096^{16*n1}
        float2 w2 = cmul(w1, w1);
        float2 w3 = cmul(w2, w1);
        float2 Pw[4], z[4];
        Pw[0] = P;
        Pw[1] = cmul(P, w1);
        Pw[2] = cmul(P, w2);
        Pw[3] = cmul(P, w3);
        z[0] = make_float2(1.f, 0.f);
        z[1] = cmul(w2, w2);                      // W256^{4*n1}
        z[2] = cmul(z[1], z[1]);
        z[3] = cmul(z[2], z[1]);
        const int wb = (hi ^ lo) + (lo << 8);
        #pragma unroll
        for (int k2 = 0; k2 < 16; ++k2) {
            float2 u = cmul(v[POS(k2)], Pw[k2 & 3]);
            if (k2 >> 2) u = cmul(u, z[k2 >> 2]);
            sd[wb + (k2 << 4)] = u;
        }
    }
    __syncthreads();

    // RT2 read: w[n1] = sd[(k3^n1) + 16*k2 + 256*n1]  (uniform 4/pair-bank)
    #pragma unroll
    for (int m = 0; m < 16; ++m)
        v[m] = sd[(lo ^ m) + (hi << 4) + (m << 8)];

    // ---- Stage C: DFT16 over n1; coalesced nontemporal stride-256 scatter ----
    dft16(v);
    float* yr = yre + off;
    float* yi = yim + off;
    #pragma unroll
    for (int k1 = 0; k1 < 16; ++k1) {
        __builtin_nontemporal_store(v[POS(k1)].x, &yr[t + (k1 << 8)]);
        __builtin_nontemporal_store(v[POS(k1)].y, &yi[t + (k1 << 8)]);
    }
}

extern "C" void kernel_launch(void* const* d_in, const int* in_sizes, int n_in,
                              void* d_out, int out_size, void* d_ws, size_t ws_size,
                              hipStream_t stream) {
    const float* xre = (const float*)d_in[0];
    const float* xim = (const float*)d_in[1];
    const int total = in_sizes[0];          // B * N
    const int rows  = total / FFT_N;        // 2048
    float* yre = (float*)d_out;
    float* yim = yre + total;
    fft4096_r16<<<dim3(rows), dim3(THREADS), 0, stream>>>(xre, xim, yre, yim);
}

// Round 7
// 26.466 us; speedup vs baseline: 1.0312x; 1.0312x over previous
//
#include <hip/hip_runtime.h>
#include <math.h>

#define FFT_N   4096
#define THREADS 256
#define RH 0.70710678118654752f
#define C16 0.92387953251128676f     // cos(2*pi/16)
#define S16 0.38268343236508977f     // sin(2*pi/16)
#define NEG2PI_256  (-2.45436926061702597e-2f)   // -2*pi/256
#define NEG2PI_4096 (-1.53398078788564123e-3f)   // -2*pi/4096

// Output-position map of dft16: X[k] lives in v[POS(k)].
#define POS(k) ((((k) & 3) << 2) | ((k) >> 2))

__device__ __forceinline__ float2 cmul(float2 a, float2 b) {
    return make_float2(a.x * b.x - a.y * b.y, a.x * b.y + a.y * b.x);
}

// Barrier WITHOUT vmcnt drain: LDS correctness only needs lgkmcnt(0).
// Keeps prefetched global loads in flight across the barrier (T3/T4).
__device__ __forceinline__ void bar_lds() {
    asm volatile("s_waitcnt lgkmcnt(0)" ::: "memory");
    __builtin_amdgcn_s_barrier();
}

// In-place DFT-4 (W4 = -i): natural in, natural out.
__device__ __forceinline__ void dft4(float2& a, float2& b, float2& c, float2& d) {
    float2 t0 = make_float2(a.x + c.x, a.y + c.y);
    float2 t1 = make_float2(a.x - c.x, a.y - c.y);
    float2 t2 = make_float2(b.x + d.x, b.y + d.y);
    float2 t3 = make_float2(b.y - d.y, d.x - b.x);   // -i * (b - d)
    a = make_float2(t0.x + t2.x, t0.y + t2.y);
    b = make_float2(t1.x + t3.x, t1.y + t3.y);
    c = make_float2(t0.x - t2.x, t0.y - t2.y);
    d = make_float2(t1.x - t3.x, t1.y - t3.y);
}

// Multiply by W16^E = exp(-2*pi*i*E/16); constant-folded forms.
template<int E>
__device__ __forceinline__ float2 mw16(float2 z) {
    if constexpr (E == 0) return z;
    else if constexpr (E == 4) return make_float2(z.y, -z.x);                    // -i
    else if constexpr (E == 2) return make_float2(RH * (z.x + z.y), RH * (z.y - z.x));
    else if constexpr (E == 6) return make_float2(RH * (z.y - z.x), -RH * (z.x + z.y));
    else if constexpr (E == 1) return cmul(z, make_float2(C16, -S16));
    else if constexpr (E == 3) return cmul(z, make_float2(S16, -C16));
    else /* E == 9 */          return cmul(z, make_float2(-C16, S16));
}

// 16-point DFT, natural input order; output X[k] at v[POS(k)].
__device__ __forceinline__ void dft16(float2 (&v)[16]) {
    dft4(v[0], v[4], v[8],  v[12]);
    dft4(v[1], v[5], v[9],  v[13]);
    dft4(v[2], v[6], v[10], v[14]);
    dft4(v[3], v[7], v[11], v[15]);
    v[5]  = mw16<1>(v[5]);   v[9]  = mw16<2>(v[9]);   v[13] = mw16<3>(v[13]);
    v[6]  = mw16<2>(v[6]);   v[10] = mw16<4>(v[10]);  v[14] = mw16<6>(v[14]);
    v[7]  = mw16<3>(v[7]);   v[11] = mw16<6>(v[11]);  v[15] = mw16<9>(v[15]);
    dft4(v[0],  v[1],  v[2],  v[3]);
    dft4(v[4],  v[5],  v[6],  v[7]);
    dft4(v[8],  v[9],  v[10], v[11]);
    dft4(v[12], v[13], v[14], v[15]);
}

__device__ __forceinline__ void load_row(float2 (&v)[16],
                                         const float* __restrict__ xr,
                                         const float* __restrict__ xi, int t) {
    #pragma unroll
    for (int n3 = 0; n3 < 16; ++n3) {
        v[n3].x = xr[t + (n3 << 8)];
        v[n3].y = xi[t + (n3 << 8)];
    }
}

// One full 4096-point row: verified round-5 skeleton, barriers swapped to bar_lds.
// 4096 = 16*16*16 DIT: n = n1 + 16*n2 + 256*n3, k = k3 + 16*k2 + 256*k1.
__device__ __forceinline__ void process_row(float2 (&v)[16], float2* __restrict__ sd,
                                            int t, int lo, int hi,
                                            float* __restrict__ yr,
                                            float* __restrict__ yi) {
    // ---- Stage A: DFT16 over n3 (thread t = n1 + 16*n2) ----
    dft16(v);

    // Twiddle W256^{n2*k3} = b[k3&3]*c[k3>>2]; write RT1: sd[t + 256*k3]
    {
        float sn, cs;
        __sincosf((float)hi * NEG2PI_256, &sn, &cs);
        float2 b[4], c[4];
        b[0] = make_float2(1.f, 0.f);
        b[1] = make_float2(cs, sn);
        b[2] = cmul(b[1], b[1]);
        b[3] = cmul(b[2], b[1]);
        c[0] = make_float2(1.f, 0.f);
        c[1] = cmul(b[2], b[2]);        // W256^{4*hi}
        c[2] = cmul(c[1], c[1]);
        c[3] = cmul(c[2], c[1]);
        #pragma unroll
        for (int k3 = 0; k3 < 16; ++k3) {
            float2 z = v[POS(k3)];
            if (k3 & 3)  z = cmul(z, b[k3 & 3]);
            if (k3 >> 2) z = cmul(z, c[k3 >> 2]);
            sd[t + (k3 << 8)] = z;
        }
    }
    bar_lds();

    // RT1 read: u[n2] = sd[n1 + 16*n2 + 256*k3]
    #pragma unroll
    for (int n2 = 0; n2 < 16; ++n2)
        v[n2] = sd[lo + (n2 << 4) + (hi << 8)];
    bar_lds();   // sd reused by RT2 writes

    // ---- Stage B: DFT16 over n2 ----
    dft16(v);

    // Twiddle W4096^{n1*(k3+16*k2)} = Pw[k2&3]*z[k2>>2]; write RT2 XOR-swizzled:
    // sd[(k3^n1) + 16*k2 + 256*n1]
    {
        float sn, cs;
        __sincosf((float)(lo * hi) * NEG2PI_4096, &sn, &cs);
        const float2 P = make_float2(cs, sn);
        __sincosf((float)lo * NEG2PI_256, &sn, &cs);
        float2 w1 = make_float2(cs, sn);          // W4096^{16*n1}
        float2 w2 = cmul(w1, w1);
        float2 w3 = cmul(w2, w1);
        float2 Pw[4], z[4];
        Pw[0] = P;
        Pw[1] = cmul(P, w1);
        Pw[2] = cmul(P, w2);
        Pw[3] = cmul(P, w3);
        z[0] = make_float2(1.f, 0.f);
        z[1] = cmul(w2, w2);                      // W256^{4*n1}
        z[2] = cmul(z[1], z[1]);
        z[3] = cmul(z[2], z[1]);
        const int wb = (hi ^ lo) + (lo << 8);
        #pragma unroll
        for (int k2 = 0; k2 < 16; ++k2) {
            float2 u = cmul(v[POS(k2)], Pw[k2 & 3]);
            if (k2 >> 2) u = cmul(u, z[k2 >> 2]);
            sd[wb + (k2 << 4)] = u;
        }
    }
    bar_lds();

    // RT2 read: w[n1] = sd[(k3^n1) + 16*k2 + 256*n1]
    #pragma unroll
    for (int m = 0; m < 16; ++m)
        v[m] = sd[(lo ^ m) + (hi << 4) + (m << 8)];

    // ---- Stage C: DFT16 over n1; coalesced nontemporal stride-256 scatter ----
    dft16(v);
    #pragma unroll
    for (int k1 = 0; k1 < 16; ++k1) {
        __builtin_nontemporal_store(v[POS(k1)].x, &yr[t + (k1 << 8)]);
        __builtin_nontemporal_store(v[POS(k1)].y, &yi[t + (k1 << 8)]);
    }
}

// Two rows per block, software-pipelined: row1's global loads are issued
// before row0's compute and stay in flight across the (non-draining) barriers.
__global__ __launch_bounds__(THREADS)
void fft4096_r16p(const float* __restrict__ xre, const float* __restrict__ xim,
                  float* __restrict__ yre, float* __restrict__ yim)
{
    __shared__ float2 sd[FFT_N];   // 32 KB

    const int t  = threadIdx.x;
    const int lo = t & 15;
    const int hi = t >> 4;
    const size_t off0 = (size_t)(2 * blockIdx.x) * FFT_N;
    const size_t off1 = off0 + FFT_N;

    float2 va[16], vb[16];
    load_row(va, xre + off0, xim + off0, t);
    load_row(vb, xre + off1, xim + off1, t);   // prefetch: consumed after row 0

    process_row(va, sd, t, lo, hi, yre + off0, yim + off0);
    bar_lds();   // all waves done with sd (row0 RT2 reads) before row1 RT1 writes
    process_row(vb, sd, t, lo, hi, yre + off1, yim + off1);
}

extern "C" void kernel_launch(void* const* d_in, const int* in_sizes, int n_in,
                              void* d_out, int out_size, void* d_ws, size_t ws_size,
                              hipStream_t stream) {
    const float* xre = (const float*)d_in[0];
    const float* xim = (const float*)d_in[1];
    const int total = in_sizes[0];          // B * N
    const int rows  = total / FFT_N;        // 2048
    float* yre = (float*)d_out;
    float* yim = yre + total;
    fft4096_r16p<<<dim3(rows / 2), dim3(THREADS), 0, stream>>>(xre, xim, yre, yim);
}